// Round 5
// baseline (203.900 us; speedup 1.0000x reference)
//
#include <hip/hip_runtime.h>
#include <hip/hip_bf16.h>
#include <stdint.h>

// out[4096,4096] = x[4096,2048] @ matrix[0,4096,2048]^T   (fp32 in/out)
// R8: cast pass unchanged. GEMM: 256x256 tile, 8 waves, BK=64, 128 KiB dbuf
// LDS -- now with ONE-PHASE READ-LOOKAHEAD: ds_reads issued in phase k feed
// phase k+1's MFMA, so every MFMA's operands are ~620 cyc old (no wait) and
// the DS pipe drains the next burst under the current MFMA cluster. R4/R7
// diagnosis: lgkmcnt(0)-per-phase (or same-phase operand reads) serialize
// read-bursts against MFMA-bursts CU-wide (m218: counted-vs-drain IS the
// 8-phase gain). Zero lgkm drains here (compiler emits precise counted
// waits); per tile: 1 stale vmcnt(0) + 2 s_barriers (buffer-admit, stage-WAR),
// phases pinned by sched_barrier(0) not lockstep. Phase order per tile:
// Q1(aLo,bHi)->Q0(aLo,bLo)->Q3(aHi,bLo)->Q2(aHi,bHi); issue P1:bLo(4),
// P2:aHi(8), P3:aLo(t+1)(8), P4:bHi(t+1)(4)+STAGE(t+2)(8). bHi parity-
// double-buffered (the only group live across its successor's read).
// R3's XOR chunk swizzle (0 conflicts) + m89 C/D layout retained.

#define GAS __attribute__((address_space(1)))
#define LAS __attribute__((address_space(3)))

typedef __bf16 bf16x8 __attribute__((ext_vector_type(8)));
typedef float f32x4 __attribute__((ext_vector_type(4)));

static __device__ __forceinline__ unsigned short f2bf(float f) {
  union { float f; uint32_t u; } a; a.f = f;
  uint32_t u = a.u;
  u += 0x7FFFu + ((u >> 16) & 1u);   // round-to-nearest-even
  return (unsigned short)(u >> 16);
}

__global__ void cvt_f32_to_bf16(const float4* __restrict__ x,
                                const float4* __restrict__ m,
                                ushort4* __restrict__ xo,
                                ushort4* __restrict__ mo) {
  const int i = blockIdx.x * blockDim.x + threadIdx.x;
  const float4* __restrict__ src = blockIdx.y ? m : x;
  ushort4* __restrict__ dst      = blockIdx.y ? mo : xo;
  float4 v = src[i];
  ushort4 o;
  o.x = f2bf(v.x); o.y = f2bf(v.y); o.z = f2bf(v.z); o.w = f2bf(v.w);
  dst[i] = o;
}

#define MFMA16(a, b, c) __builtin_amdgcn_mfma_f32_16x16x32_bf16((a), (b), (c), 0, 0, 0)
#define SB0 __builtin_amdgcn_sched_barrier(0)

__global__ __launch_bounds__(512, 2)
void gemm_bt_bf16(const unsigned short* __restrict__ A,
                  const unsigned short* __restrict__ B,
                  float* __restrict__ C) {
  constexpr int K     = 2048;
  constexpr int N     = 4096;
  constexpr int NT    = K / 64;    // 32 K-tiles
  constexpr int NITER = NT / 2;    // 16 (2 tiles/iter, even in buf0, odd buf1)

  __shared__ __align__(16) unsigned short lds[2][2][256 * 64];   // 128 KiB

  const int tid  = threadIdx.x;
  const int wave = tid >> 6;
  const int lane = tid & 63;
  const int wm   = wave >> 2;   // 0..1
  const int wn   = wave & 3;    // 0..3

  // XCD-chunked swizzle (bijective over 256 blocks).
  const int bid = blockIdx.x;
  const int tm  = (bid & 7) * 2 + ((bid >> 3) >> 4);
  const int tn  = (bid >> 3) & 15;
  const int bM  = tm * 256;
  const int bN  = tn * 256;

  const int quad = lane >> 4;   // 0..3
  const int l15  = lane & 15;
  const int mx   = l15 & 7;

  // Staging: per tile 8 insts/wave; quarter q rows q*64 + wave*8 + lr2.
  const int lr2 = lane >> 3;              // 0..7
  const int lcc = (lane & 7) ^ lr2;       // pre-swizzled source chunk
  const size_t aSB = (size_t)(bM + wave * 8 + lr2) * K + lcc * 8;
  const size_t bSB = (size_t)(bN + wave * 8 + lr2) * K + lcc * 8;

  // Fragment read offsets (elems). Physical chunk = (ks*4+quad)^mx.
  const int aOff = (wm * 128 + l15) * 64;
  const int bOff = (wn * 64  + l15) * 64;
  const int ko0  = ((0 * 4 + quad) ^ mx) << 3;
  const int ko1  = ((1 * 4 + quad) ^ mx) << 3;

  f32x4 acc[8][4] = {};
  bf16x8 aLo[4][2], aHi[4][2], bLo[2][2], bhA[2][2], bhB[2][2];

#define STAGE_T(tau, bb) do {                                                              \
    _Pragma("unroll")                                                                      \
    for (int q = 0; q < 4; ++q)                                                            \
      __builtin_amdgcn_global_load_lds(                                                    \
        (const GAS void*)(A + aSB + (size_t)q * 64 * K + (size_t)(tau) * 64),              \
        (LAS void*)(&lds[bb][0][(q * 64 + wave * 8) * 64]), 16, 0, 0);                     \
    _Pragma("unroll")                                                                      \
    for (int q = 0; q < 4; ++q)                                                            \
      __builtin_amdgcn_global_load_lds(                                                    \
        (const GAS void*)(B + bSB + (size_t)q * 64 * K + (size_t)(tau) * 64),              \
        (LAS void*)(&lds[bb][1][(q * 64 + wave * 8) * 64]), 16, 0, 0);                     \
  } while (0)

  // One K-tile: cur buf (AsC,BsC), next buf (AsN,BsN), bHi read/write parity.
  // P1{iss bLo | Q1} P2{iss aHi | Q0} P3{vm0;bar; iss aLo' | Q3 ;bar}
  // P4{STAGE t+2; iss bHi' | Q2}
#define TILE(AsC, BsC, AsN, BsN, BHRD, BHWR, NEXTOK, STGOK, TAU2, SBUF)            \
  do {                                                                             \
    /* ---- P1 ---- */                                                             \
    _Pragma("unroll")                                                              \
    for (int j = 0; j < 2; ++j) {                                                  \
      bLo[j][0] = *(const bf16x8*)((BsC) + bOff + j * 1024 + ko0);                 \
      bLo[j][1] = *(const bf16x8*)((BsC) + bOff + j * 1024 + ko1);                 \
    }                                                                              \
    SB0;                                                                           \
    __builtin_amdgcn_s_setprio(1);                                                 \
    _Pragma("unroll")                                                              \
    for (int i = 0; i < 4; ++i)                                                    \
      _Pragma("unroll")                                                            \
      for (int j = 0; j < 2; ++j) {                                                \
        acc[i][2 + j] = MFMA16(aLo[i][0], BHRD[j][0], acc[i][2 + j]);              \
        acc[i][2 + j] = MFMA16(aLo[i][1], BHRD[j][1], acc[i][2 + j]);              \
      }                                                                            \
    __builtin_amdgcn_s_setprio(0);                                                 \
    SB0;                                                                           \
    /* ---- P2 ---- */                                                             \
    _Pragma("unroll")                                                              \
    for (int i = 0; i < 4; ++i) {                                                  \
      aHi[i][0] = *(const bf16x8*)((AsC) + aOff + (4 + i) * 1024 + ko0);           \
      aHi[i][1] = *(const bf16x8*)((AsC) + aOff + (4 + i) * 1024 + ko1);           \
    }                                                                              \
    SB0;                                                                           \
    __builtin_amdgcn_s_setprio(1);                                                 \
    _Pragma("unroll")                                                              \
    for (int i = 0; i < 4; ++i)                                                    \
      _Pragma("unroll")                                                            \
      for (int j = 0; j < 2; ++j) {                                                \
        acc[i][j] = MFMA16(aLo[i][0], bLo[j][0], acc[i][j]);                       \
        acc[i][j] = MFMA16(aLo[i][1], bLo[j][1], acc[i][j]);                       \
      }                                                                            \
    __builtin_amdgcn_s_setprio(0);                                                 \
    SB0;                                                                           \
    /* ---- P3: admit next buffer, lookahead aLo(t+1), MFMA Q3 ---- */             \
    asm volatile("s_waitcnt vmcnt(0)" ::: "memory");  /* stale: stage(t+1) */      \
    SB0;                                                                           \
    __builtin_amdgcn_s_barrier();                     /* all waves: t+1 landed */  \
    SB0;                                                                           \
    if (NEXTOK) {                                                                  \
      _Pragma("unroll")                                                            \
      for (int i = 0; i < 4; ++i) {                                                \
        aLo[i][0] = *(const bf16x8*)((AsN) + aOff + i * 1024 + ko0);               \
        aLo[i][1] = *(const bf16x8*)((AsN) + aOff + i * 1024 + ko1);               \
      }                                                                            \
    }                                                                              \
    SB0;                                                                           \
    __builtin_amdgcn_s_setprio(1);                                                 \
    _Pragma("unroll")                                                              \
    for (int i = 0; i < 4; ++i)                                                    \
      _Pragma("unroll")                                                            \
      for (int j = 0; j < 2; ++j) {                                                \
        acc[4 + i][j] = MFMA16(aHi[i][0], bLo[j][0], acc[4 + i][j]);               \
        acc[4 + i][j] = MFMA16(aHi[i][1], bLo[j][1], acc[4 + i][j]);               \
      }                                                                            \
    __builtin_amdgcn_s_setprio(0);                                                 \
    SB0;                                                                           \
    __builtin_amdgcn_s_barrier();   /* WAR: all buf-cur reads consumed */          \
    SB0;                                                                           \
    /* ---- P4: stage t+2 into cur, lookahead bHi(t+1), MFMA Q2 ---- */            \
    if (STGOK) STAGE_T(TAU2, SBUF);                                                \
    if (NEXTOK) {                                                                  \
      _Pragma("unroll")                                                            \
      for (int j = 0; j < 2; ++j) {                                                \
        BHWR[j][0] = *(const bf16x8*)((BsN) + bOff + (2 + j) * 1024 + ko0);        \
        BHWR[j][1] = *(const bf16x8*)((BsN) + bOff + (2 + j) * 1024 + ko1);        \
      }                                                                            \
    }                                                                              \
    SB0;                                                                           \
    __builtin_amdgcn_s_setprio(1);                                                 \
    _Pragma("unroll")                                                              \
    for (int i = 0; i < 4; ++i)                                                    \
      _Pragma("unroll")                                                            \
      for (int j = 0; j < 2; ++j) {                                                \
        acc[4 + i][2 + j] = MFMA16(aHi[i][0], BHRD[j][0], acc[4 + i][2 + j]);      \
        acc[4 + i][2 + j] = MFMA16(aHi[i][1], BHRD[j][1], acc[4 + i][2 + j]);      \
      }                                                                            \
    __builtin_amdgcn_s_setprio(0);                                                 \
    SB0;                                                                           \
  } while (0)

  const unsigned short* A0 = lds[0][0];
  const unsigned short* B0 = lds[0][1];
  const unsigned short* A1 = lds[1][0];
  const unsigned short* B1 = lds[1][1];

  // Prologue: stage tiles 0,1; vmcnt(8) = tile0 landed (tile1 in flight);
  // preload tile0's aLo + bhA (the operands P1/P4 expect from "P3/P4(t-1)").
  STAGE_T(0, 0);
  STAGE_T(1, 1);
  asm volatile("s_waitcnt vmcnt(8)" ::: "memory");
  SB0;
  __builtin_amdgcn_s_barrier();
  SB0;
#pragma unroll
  for (int i = 0; i < 4; ++i) {
    aLo[i][0] = *(const bf16x8*)(A0 + aOff + i * 1024 + ko0);
    aLo[i][1] = *(const bf16x8*)(A0 + aOff + i * 1024 + ko1);
  }
#pragma unroll
  for (int j = 0; j < 2; ++j) {
    bhA[j][0] = *(const bf16x8*)(B0 + bOff + (2 + j) * 1024 + ko0);
    bhA[j][1] = *(const bf16x8*)(B0 + bOff + (2 + j) * 1024 + ko1);
  }
  SB0;

#pragma unroll 1
  for (int it = 0; it < NITER; ++it) {
    const bool nlast = (it < NITER - 1);
    // even tile t=2it (buf0): t+1 always valid; stage t+2 iff not last iter
    TILE(A0, B0, A1, B1, bhA, bhB, true, nlast, 2 * it + 2, 0);
    // odd tile t=2it+1 (buf1): t+1,t+2 valid iff not last iter
    TILE(A1, B1, A0, B0, bhB, bhA, nlast, nlast, 2 * it + 3, 1);
  }
#undef TILE
#undef STAGE_T

  // Epilogue: C/D layout col=lane&15, row=quad*4+reg (m89-verified).
#pragma unroll
  for (int i = 0; i < 8; ++i) {
    const int row0 = bM + wm * 128 + i * 16 + quad * 4;
#pragma unroll
    for (int j = 0; j < 4; ++j) {
      const int col = bN + wn * 64 + j * 16 + l15;
#pragma unroll
      for (int tt = 0; tt < 4; ++tt)
        C[(size_t)(row0 + tt) * N + col] = acc[i][j][tt];
    }
  }
}

extern "C" void kernel_launch(void* const* d_in, const int* in_sizes, int n_in,
                              void* d_out, int out_size, void* d_ws, size_t ws_size,
                              hipStream_t stream) {
  const float* x   = (const float*)d_in[0];   // [4096, 2048]
  const float* mat = (const float*)d_in[1];   // [1, 4096, 2048]
  float* out = (float*)d_out;                 // [4096, 4096]

  constexpr size_t ELEMS = 4096ull * 2048ull;
  unsigned short* xb = (unsigned short*)d_ws;
  unsigned short* mb = xb + ELEMS;

  dim3 cgrid((unsigned)(ELEMS / 4 / 256), 2);
  cvt_f32_to_bf16<<<cgrid, 256, 0, stream>>>((const float4*)x, (const float4*)mat,
                                             (ushort4*)xb, (ushort4*)mb);

  // 256 blocks = 16x16 tiles of 256x256, 1 block/CU, XCD-swizzled in-kernel.
  gemm_bt_bf16<<<dim3(256), 512, 0, stream>>>(xb, mb, out);
}

// Round 6
// 190.918 us; speedup vs baseline: 1.0680x; 1.0680x over previous
//
#include <hip/hip_runtime.h>
#include <hip/hip_bf16.h>
#include <stdint.h>

// out[4096,4096] = x[4096,2048] @ matrix[0,4096,2048]^T   (fp32 in/out)
// R9: cast pass unchanged. GEMM: back to R3's proven geometry (256x128 tile,
// 4 waves of 128x64, 2 blocks/CU) but B BYPASSES LDS: fragments load straight
// from global into VGPRs (B-slice/block = 512KB, L2-resident; B total 16MB,
// L3-resident). Rationale: R3..R8 all plateaued at ~5200cyc/K-tile because
// LDS traffic (192KB rd + 64KB wr per 256-tile) exceeds the MFMA time; no
// schedule can beat a pipe that's over-subscribed. Direct-B removes B's
// ds_write AND ds_read: LDS/CU/tile ~2300->~1500cyc < MFMA 2484 -> MFMA-bound.
// LDS halves to 64KB -> 2 blocks/CU restored (the only overlap that ever
// worked). Sync: ONE barrier + lgkm(0) per tile; all vmem waits counted by
// construction (bF(t) issued after STAGE(t) -> compiler's bF wait drains
// stage exactly when needed, never early). A keeps R3's XOR chunk swizzle
// (0 conflicts) + m89 C/D layout.

#define GAS __attribute__((address_space(1)))
#define LAS __attribute__((address_space(3)))

typedef __bf16 bf16x8 __attribute__((ext_vector_type(8)));
typedef float f32x4 __attribute__((ext_vector_type(4)));

static __device__ __forceinline__ unsigned short f2bf(float f) {
  union { float f; uint32_t u; } a; a.f = f;
  uint32_t u = a.u;
  u += 0x7FFFu + ((u >> 16) & 1u);   // round-to-nearest-even
  return (unsigned short)(u >> 16);
}

__global__ void cvt_f32_to_bf16(const float4* __restrict__ x,
                                const float4* __restrict__ m,
                                ushort4* __restrict__ xo,
                                ushort4* __restrict__ mo) {
  const int i = blockIdx.x * blockDim.x + threadIdx.x;
  const float4* __restrict__ src = blockIdx.y ? m : x;
  ushort4* __restrict__ dst      = blockIdx.y ? mo : xo;
  float4 v = src[i];
  ushort4 o;
  o.x = f2bf(v.x); o.y = f2bf(v.y); o.z = f2bf(v.z); o.w = f2bf(v.w);
  dst[i] = o;
}

#define MFMA16(a, b, c) __builtin_amdgcn_mfma_f32_16x16x32_bf16((a), (b), (c), 0, 0, 0)
#define SB0 __builtin_amdgcn_sched_barrier(0)

// C[M,N] = A[M,K]*B[N,K]^T, M=4096, N=4096, K=2048. 256 threads = 4 waves.
// Block tile 256x128; wave (wm=wave&1, wn=wave>>1) owns rows wm*128..+128,
// cols wn*64..+64 as acc[8][4] of 16x16x32 frags. BK=64, NT=32.
// A: LDS double-buffered As[2][256*64] (64KB), XOR chunk swizzle, staged by
//    global_load_lds (8 insts/wave/tile).
// B: NO LDS. Per wave 8 global_load_dwordx4/tile: lane(l15,quad) of frag
//    (j, ks) reads B[bN+wn*64+j*16+l15][t*64+ks*32+quad*8 .. +8) -- the MFMA
//    B-fragment layout directly (16 rows x 64B contiguous per inst).
// Per tile t (buf p=t&1):
//   reads aF0-3 (8 ds) | MFMA r0-3 (32; compiler vmcnt wait on bF(t) also
//   retires stage(t+1), which is older) | reads aF4-7 into same regs |
//   MFMA r4-7 (32) | lgkm(0) | barrier  <- buf p free, stage(t+1) propagated
//   STAGE(t+2 -> p) | BLOAD(t+1)        <- issue-only; waits land next tile
__global__ __launch_bounds__(256, 2)
void gemm_bt_bf16(const unsigned short* __restrict__ A,
                  const unsigned short* __restrict__ B,
                  float* __restrict__ C) {
  constexpr int K  = 2048;
  constexpr int N  = 4096;
  constexpr int NT = K / 64;   // 32 K-tiles

  __shared__ __align__(16) unsigned short As[2][256 * 64];   // 64 KB

  const int tid  = threadIdx.x;
  const int wave = tid >> 6;
  const int lane = tid & 63;
  const int wm   = wave & 1;
  const int wn   = wave >> 1;
  const int bM   = blockIdx.y * 256;
  const int bN   = blockIdx.x * 128;

  const int quad = lane >> 4;   // 0..3
  const int l15  = lane & 15;
  const int mx   = l15 & 7;

  // A staging (R3's): wave covers rows [wave*64, wave*64+64), 8 insts of
  // 8 rows; lane -> row lr, pre-swizzled source chunk lc.
  const int lr = lane >> 3;
  const int lc = (lane & 7) ^ lr;
  const size_t aBase = (size_t)(bM + wave * 64 + lr) * K + lc * 8;
  const int aLds = wave * 64 * 64;   // elems

  // A fragment reads: physical chunk = (ks*4+quad)^mx.
  const int aOff = (wm * 128 + l15) * 64;
  const int ko0  = ((0 * 4 + quad) ^ mx) << 3;
  const int ko1  = ((1 * 4 + quad) ^ mx) << 3;

  // B fragment base: row = bN + wn*64 + l15 (+j*16), k = quad*8 (+t*64+ks*32)
  const unsigned short* bPtr = B + (size_t)(bN + wn * 64 + l15) * K + quad * 8;

  f32x4 acc[8][4] = {};
  bf16x8 aF[4][2], bF[4][2];

#define STAGE(tau, pp) do {                                                                \
    const size_t kk_ = (size_t)(tau) * 64;                                                 \
    _Pragma("unroll")                                                                      \
    for (int u = 0; u < 8; ++u)                                                            \
      __builtin_amdgcn_global_load_lds((const GAS void*)(A + aBase + kk_ + (size_t)u * 8 * K), \
                                       (LAS void*)(&As[pp][aLds + u * 512]), 16, 0, 0);    \
  } while (0)

#define BLOAD(tau) do {                                                                    \
    const size_t kk_ = (size_t)(tau) * 64;                                                 \
    _Pragma("unroll")                                                                      \
    for (int j = 0; j < 4; ++j) {                                                          \
      bF[j][0] = *(const bf16x8*)(bPtr + (size_t)j * 16 * K + kk_);                        \
      bF[j][1] = *(const bf16x8*)(bPtr + (size_t)j * 16 * K + kk_ + 32);                   \
    }                                                                                      \
  } while (0)

  // Prologue: stage tiles 0,1; load bF(0) (newest -> its wait covers both
  // stages at t=0, one-time). Explicit vmcnt(16)+barrier admits buf0.
  STAGE(0, 0);
  STAGE(1, 1);
  BLOAD(0);
  asm volatile("s_waitcnt vmcnt(16)" ::: "memory");
  SB0;
  __builtin_amdgcn_s_barrier();
  SB0;

#pragma unroll 1
  for (int t = 0; t < NT; ++t) {
    const unsigned short* Ap = As[t & 1];

    // ---- ds_read rows 0-3 (8 x b128) ----
#pragma unroll
    for (int i = 0; i < 4; ++i) {
      aF[i][0] = *(const bf16x8*)(Ap + aOff + i * 1024 + ko0);
      aF[i][1] = *(const bf16x8*)(Ap + aOff + i * 1024 + ko1);
    }
    SB0;
    // ---- MFMA rows 0-3 (32). Compiler waits bF(t) here; bF(t) is newer
    // than stage(t+1), so that wait also retires stage(t+1). ----
    __builtin_amdgcn_s_setprio(1);
#pragma unroll
    for (int i = 0; i < 4; ++i)
#pragma unroll
      for (int j = 0; j < 4; ++j) {
        acc[i][j] = MFMA16(aF[i][0], bF[j][0], acc[i][j]);
        acc[i][j] = MFMA16(aF[i][1], bF[j][1], acc[i][j]);
      }
    __builtin_amdgcn_s_setprio(0);
    SB0;
    // ---- ds_read rows 4-7 into the same regs (WAR-safe: in-order issue) ----
#pragma unroll
    for (int i = 0; i < 4; ++i) {
      aF[i][0] = *(const bf16x8*)(Ap + aOff + (4 + i) * 1024 + ko0);
      aF[i][1] = *(const bf16x8*)(Ap + aOff + (4 + i) * 1024 + ko1);
    }
    SB0;
    // ---- MFMA rows 4-7 (32) ----
    __builtin_amdgcn_s_setprio(1);
#pragma unroll
    for (int i = 0; i < 4; ++i)
#pragma unroll
      for (int j = 0; j < 4; ++j) {
        acc[4 + i][j] = MFMA16(aF[i][0], bF[j][0], acc[4 + i][j]);
        acc[4 + i][j] = MFMA16(aF[i][1], bF[j][1], acc[4 + i][j]);
      }
    __builtin_amdgcn_s_setprio(0);
    SB0;
    // ---- single sync point: my reads of buf p are done -> barrier frees
    // buf p for STAGE(t+2) and (transitively) publishes stage(t+1). ----
    asm volatile("s_waitcnt lgkmcnt(0)" ::: "memory");
    SB0;
    __builtin_amdgcn_s_barrier();
    SB0;
    // ---- issue-only: next stage + next B fragments (waits land next tile) --
    if (t + 2 < NT) STAGE(t + 2, t & 1);
    if (t + 1 < NT) BLOAD(t + 1);
    SB0;
  }
#undef STAGE
#undef BLOAD

  // Epilogue: C/D layout col=lane&15, row=quad*4+reg (m89-verified).
#pragma unroll
  for (int i = 0; i < 8; ++i) {
    const int row0 = bM + wm * 128 + i * 16 + quad * 4;
#pragma unroll
    for (int j = 0; j < 4; ++j) {
      const int col = bN + wn * 64 + j * 16 + l15;
#pragma unroll
      for (int tt = 0; tt < 4; ++tt)
        C[(size_t)(row0 + tt) * N + col] = acc[i][j][tt];
    }
  }
}

extern "C" void kernel_launch(void* const* d_in, const int* in_sizes, int n_in,
                              void* d_out, int out_size, void* d_ws, size_t ws_size,
                              hipStream_t stream) {
  const float* x   = (const float*)d_in[0];   // [4096, 2048]
  const float* mat = (const float*)d_in[1];   // [1, 4096, 2048]
  float* out = (float*)d_out;                 // [4096, 4096]

  constexpr size_t ELEMS = 4096ull * 2048ull;
  unsigned short* xb = (unsigned short*)d_ws;
  unsigned short* mb = xb + ELEMS;

  dim3 cgrid((unsigned)(ELEMS / 4 / 256), 2);
  cvt_f32_to_bf16<<<cgrid, 256, 0, stream>>>((const float4*)x, (const float4*)mat,
                                             (ushort4*)xb, (ushort4*)mb);

  // 512 blocks: grid.x = N/128 = 32, grid.y = M/256 = 16 -> 2 blocks/CU.
  // Natural order keeps each XCD on 4 B-column strips (2MB, L2-resident).
  gemm_bt_bf16<<<dim3(32, 16), 256, 0, stream>>>(xb, mb, out);
}